// Round 4
// baseline (152.575 us; speedup 1.0000x reference)
//
#include <hip/hip_runtime.h>

typedef unsigned short u16;
typedef short bf16x8 __attribute__((ext_vector_type(8)));
typedef float f32x4 __attribute__((ext_vector_type(4)));

#define BATCH 2
#define SEQ   2048
#define CH    1024
#define NHEAD 16
#define HDIM  64
#define ROWS  (BATCH*SEQ)   // 4096

// swizzled LDS index for [*][64] bf16 tiles: breaks 128B-row bank conflicts
#define SWZ(r_, c_) (((r_)*64) + ((c_) ^ (((r_)&7)*8)))

__device__ __forceinline__ u16 f2b(float f) {
  unsigned u = __builtin_bit_cast(unsigned, f);
  u += 0x7FFFu + ((u >> 16) & 1u);
  return (u16)(u >> 16);
}
__device__ __forceinline__ float b2f(u16 h) {
  unsigned u = ((unsigned)h) << 16;
  return __builtin_bit_cast(float, u);
}
__device__ __forceinline__ float exp2_fast(float x) {
  float r; asm("v_exp_f32 %0, %1" : "=v"(r) : "v"(x)); return r;
}
__device__ __forceinline__ unsigned cvt_pk_bf16(float a, float b) {
  unsigned r; asm("v_cvt_pk_bf16_f32 %0, %1, %2" : "=v"(r) : "v"(a), "v"(b)); return r;
}

__device__ __forceinline__ void gload_lds16(const void* g, void* l) {
  __builtin_amdgcn_global_load_lds(
      (const __attribute__((address_space(1))) unsigned int*)g,
      (__attribute__((address_space(3))) unsigned int*)l, 16, 0, 0);
}

// ---------- dtype probe: flag=1 -> storage is bf16, flag=0 -> f32 ----------
__global__ void csa_detect(const u16* __restrict__ x, int* flag) {
  int t = threadIdx.x;
  bool ok = true;
  for (int i = t; i < 2048; i += 256) {
    float v = b2f(x[i]);
    ok = ok && (__builtin_fabsf(v) < 1e4f);   // NaN -> false
  }
  int wok = __all((int)ok);
  __shared__ int s[4];
  if ((t & 63) == 0) s[t >> 6] = wok;
  __syncthreads();
  if (t == 0) flag[0] = (s[0] & s[1] & s[2] & s[3]);
}

// ---------- x -> bf16 [4096][1024] ----------
__global__ void csa_convert_x(const void* __restrict__ in, u16* __restrict__ out,
                              int n8, const int* __restrict__ flagp) {
  int i = blockIdx.x * 256 + threadIdx.x;
  if (i >= n8) return;
  if (*flagp) {
    ((uint4*)out)[i] = ((const uint4*)in)[i];
  } else {
    const float4* f4 = (const float4*)in;
    float4 v0 = f4[2*i], v1 = f4[2*i+1];
    ushort4 o0, o1;
    o0.x = f2b(v0.x); o0.y = f2b(v0.y); o0.z = f2b(v0.z); o0.w = f2b(v0.w);
    o1.x = f2b(v1.x); o1.y = f2b(v1.y); o1.z = f2b(v1.z); o1.w = f2b(v1.w);
    ((ushort4*)out)[2*i]   = o0;
    ((ushort4*)out)[2*i+1] = o1;
  }
}

__global__ void csa_convert_bias(const void* __restrict__ in, float* __restrict__ out,
                                 int n, const int* __restrict__ flagp) {
  int i = blockIdx.x * 256 + threadIdx.x;
  if (i >= n) return;
  out[i] = (*flagp) ? b2f(((const u16*)in)[i]) : ((const float*)in)[i];
}

// ---------- W[R][C] -> Wt[C][R] bf16 ----------
__global__ void csa_transpose(const void* __restrict__ in, u16* __restrict__ out,
                              int R, int C, const int* __restrict__ flagp) {
  __shared__ float tile[32][33];
  const int flag = *flagp;
  const int bx = blockIdx.x * 32, by = blockIdx.y * 32;
  const int tx = threadIdx.x, ty = threadIdx.y;
  #pragma unroll
  for (int j = 0; j < 4; ++j) {
    int r = by + ty + j*8, c = bx + tx;
    float v = flag ? b2f(((const u16*)in)[(size_t)r*C + c])
                   : ((const float*)in)[(size_t)r*C + c];
    tile[ty + j*8][tx] = v;
  }
  __syncthreads();
  #pragma unroll
  for (int j = 0; j < 4; ++j) {
    int oc = bx + ty + j*8;   // column of in = row of out
    int orr = by + tx;        // row of in   = col of out
    out[(size_t)oc*R + orr] = f2b(tile[tx][ty + j*8]);
  }
}

// ---------- GEMM: C[M=4096][N] = A[M][K] * Bt[N][K]^T + bias ----------
// 2-phase single-barrier double-buffered K-loop (T3-minimum) + XCD swizzle.
__global__ __launch_bounds__(256) void csa_gemm(
    const u16* __restrict__ A, const u16* __restrict__ Bt,
    const float* __restrict__ bias, int N, int K, int mode,
    void* __restrict__ out0, u16* __restrict__ kb, u16* __restrict__ vtb,
    const int* __restrict__ flagp)
{
  __shared__ __align__(16) u16 As[2][128*64];
  __shared__ __align__(16) u16 Bs[2][128*64];
  const int t = threadIdx.x, lane = t & 63, w = t >> 6;
  const int wm = w >> 1, wn = w & 1, g = lane >> 4, qi = lane & 15;

  // bijective XCD-aware block swizzle (nwg % 8 == 0 for both call sites):
  // each XCD gets a contiguous chunk -> consecutive bm rows share A panels in L2
  const int nbn = gridDim.x;
  const int wgid = blockIdx.y * nbn + blockIdx.x;
  const int cpx = (nbn * gridDim.y) >> 3;
  const int swz = (wgid & 7) * cpx + (wgid >> 3);
  const int bm = swz / nbn, bn = swz % nbn;

  f32x4 acc[4][4] = {};

  const u16* Ab = A  + (size_t)(bm*128)*K;
  const u16* Bb = Bt + (size_t)(bn*128)*K;
  const int srow = t >> 3;          // 0..31 within a 32-row pass
  const int scol = (t & 7) * 8;

  // prologue: stage k0=0 into buf 0
  #pragma unroll
  for (int p = 0; p < 4; ++p) {
    int row = p*32 + srow;
    gload_lds16(Ab + (size_t)row*K + scol, &As[0][p*2048 + w*512]);
    gload_lds16(Bb + (size_t)row*K + scol, &Bs[0][p*2048 + w*512]);
  }
  __syncthreads();

  int cur = 0;
  for (int k0 = 0; k0 < K; k0 += 64) {
    // prefetch next K-tile into buf^1 (flies under compute; drained at barrier)
    if (k0 + 64 < K) {
      #pragma unroll
      for (int p = 0; p < 4; ++p) {
        int row = p*32 + srow;
        gload_lds16(Ab + (size_t)row*K + (k0+64) + scol, &As[cur^1][p*2048 + w*512]);
        gload_lds16(Bb + (size_t)row*K + (k0+64) + scol, &Bs[cur^1][p*2048 + w*512]);
      }
    }
    #pragma unroll
    for (int c = 0; c < 2; ++c) {
      bf16x8 af[4], bfr[4];
      #pragma unroll
      for (int m = 0; m < 4; ++m)
        af[m] = *(const bf16x8*)&As[cur][(wm*64 + m*16 + qi)*64 + c*32 + g*8];
      #pragma unroll
      for (int n = 0; n < 4; ++n)
        bfr[n] = *(const bf16x8*)&Bs[cur][(wn*64 + n*16 + qi)*64 + c*32 + g*8];
      #pragma unroll
      for (int m = 0; m < 4; ++m)
        #pragma unroll
        for (int n = 0; n < 4; ++n)
          acc[m][n] = __builtin_amdgcn_mfma_f32_16x16x32_bf16(af[m], bfr[n], acc[m][n], 0, 0, 0);
    }
    __syncthreads();   // drains prefetch (vmcnt) + guards buffer reuse
    cur ^= 1;
  }

  if (mode == 1) {
    const int flag = *flagp;
    #pragma unroll
    for (int m = 0; m < 4; ++m) {
      const int row0 = bm*128 + wm*64 + m*16 + g*4;
      #pragma unroll
      for (int n = 0; n < 4; ++n) {
        const int col = bn*128 + wn*64 + n*16 + qi;
        const float bv = bias[col];
        if (flag) {
          u16* ob = (u16*)out0;
          #pragma unroll
          for (int r = 0; r < 4; ++r)
            ob[(size_t)(row0 + r)*N + col] = f2b(acc[m][n][r] + bv);
        } else {
          float* of = (float*)out0;
          #pragma unroll
          for (int r = 0; r < 4; ++r)
            of[(size_t)(row0 + r)*N + col] = acc[m][n][r] + bv;
        }
      }
    }
  } else {
    u16* qbo = (u16*)out0;
    #pragma unroll
    for (int m = 0; m < 4; ++m) {
      const int row0 = bm*128 + wm*64 + m*16 + g*4;
      const int bb = row0 >> 11;          // batch (no 2048-crossing: row0 % 4 == 0)
      const int t0 = row0 & 2047;
      #pragma unroll
      for (int n = 0; n < 4; ++n) {
        const int col = bn*128 + wn*64 + n*16 + qi;
        const float bv = bias[col];
        const int which = col >> 10;      // 0=q 1=k 2=v
        const int cc = col & 1023;
        const int h = cc >> 6, d = cc & 63;
        const int bh = bb*16 + h;
        if (which == 2) {
          ushort4 pw;
          pw.x = f2b(acc[m][n][0] + bv);
          pw.y = f2b(acc[m][n][1] + bv);
          pw.z = f2b(acc[m][n][2] + bv);
          pw.w = f2b(acc[m][n][3] + bv);
          *(ushort4*)&vtb[((size_t)bh*HDIM + d)*SEQ + t0] = pw;
        } else {
          u16* dst = (which == 0) ? qbo : kb;
          #pragma unroll
          for (int r = 0; r < 4; ++r)
            dst[((size_t)bh*SEQ + t0 + r)*HDIM + d] = f2b(acc[m][n][r] + bv);
        }
      }
    }
  }
}

// ---------- causal flash attention v2 ----------
// grid: x = bh (32), y = pair (16). Block processes q-tiles {p, 31-p}: every
// block does exactly 33 kt-iterations (load balance). Double-buffered K/V with
// single-barrier prefetch schedule; staging = global_load_lds w/ pre-swizzled
// per-lane source + linear LDS dest (swizzle is an XOR involution).
// Swapped QK^T (mfma(K,Q)) -> S^T[key][q]; exp2-domain softmax, scale folded
// into Q; diagonal-only masking; defer-max rescale (THR=11.5 in log2 domain).
__global__ __launch_bounds__(256) void csa_attn(
    const u16* __restrict__ qb, const u16* __restrict__ kb,
    const u16* __restrict__ vtb, u16* __restrict__ yout)
{
  const int bh = blockIdx.x, pair = blockIdx.y;
  const int bidx = bh >> 4, h = bh & 15;
  const int t = threadIdx.x, lane = t & 63, w = t >> 6;
  const int g = lane >> 4, qi = lane & 15;
  __shared__ __align__(16) u16 Ks[2][64*64];
  __shared__ __align__(16) u16 Vs[2][64*64];    // V^T tile: [d][key]
  __shared__ __align__(16) u16 Ps[4][16*64];    // per-wave P [q][key] (no barrier)

  const size_t kvbase = (size_t)bh * SEQ * HDIM;   // == bh*HDIM*SEQ for vtb
  const int srow = t >> 3;            // 0..31 within a 32-row pass
  const int ssw  = ((t >> 3) & 7) * 8;
  const int scol = ((t & 7) * 8) ^ ssw;  // pre-swizzled source column

  // loop-invariant LDS element offsets
  int offK[2][4], offPw[4], offPr[2];
  #pragma unroll
  for (int c = 0; c < 2; ++c) {
    offPr[c] = SWZ(qi, c*32 + g*8);
    #pragma unroll
    for (int s4 = 0; s4 < 4; ++s4) offK[c][s4] = SWZ(s4*16 + qi, c*32 + g*8);
  }
  #pragma unroll
  for (int s4 = 0; s4 < 4; ++s4) offPw[s4] = SWZ(qi, s4*16 + g*4);

  const float QSCALE = 0.18033688011112042f;   // 0.125 * log2(e)
  const int lq = w*16 + qi;                    // local q row within 64-tile

  for (int half = 0; half < 2; ++half) {
    const int qt = half ? (31 - pair) : pair;
    const int qrow = qt*64 + w*16;
    const int nkt = qt + 1;

    // Q fragment, pre-scaled by 0.125*log2e (exp2-domain softmax)
    bf16x8 qf[2];
    #pragma unroll
    for (int c = 0; c < 2; ++c) {
      qf[c] = *(const bf16x8*)&qb[(kvbase + (size_t)(qrow + qi)*HDIM) + c*32 + g*8];
      #pragma unroll
      for (int e = 0; e < 8; ++e)
        qf[c][e] = (short)f2b(b2f((u16)qf[c][e]) * QSCALE);
    }

    f32x4 yacc[4] = {};
    float mrun = -1e30f, srun = 0.f;

    // prologue: stage kt=0 into buf 0
    #pragma unroll
    for (int p = 0; p < 2; ++p) {
      int row = p*32 + srow;
      gload_lds16(kb  + kvbase + (size_t)row*HDIM + scol,      &Ks[0][p*2048 + w*512]);
      gload_lds16(vtb + kvbase + (size_t)row*SEQ  + scol,      &Vs[0][p*2048 + w*512]);
    }
    __syncthreads();

    int cur = 0;
    for (int kt = 0; kt < nkt; ++kt) {
      // prefetch kt+1 into buf^1 (flies under compute; drained at barrier)
      if (kt + 1 < nkt) {
        const int k1 = (kt + 1) * 64;
        #pragma unroll
        for (int p = 0; p < 2; ++p) {
          int row = p*32 + srow;
          gload_lds16(kb  + kvbase + (size_t)(k1 + row)*HDIM + scol, &Ks[cur^1][p*2048 + w*512]);
          gload_lds16(vtb + kvbase + (size_t)row*SEQ + k1 + scol,    &Vs[cur^1][p*2048 + w*512]);
        }
      }

      // S^T = K * Q^T
      f32x4 st[4] = {};
      #pragma unroll
      for (int c = 0; c < 2; ++c)
        #pragma unroll
        for (int s4 = 0; s4 < 4; ++s4) {
          bf16x8 kf = *(const bf16x8*)&Ks[cur][offK[c][s4]];
          st[s4] = __builtin_amdgcn_mfma_f32_16x16x32_bf16(kf, qf[c], st[s4], 0, 0, 0);
        }

      // diagonal-only causal mask
      if (kt == nkt - 1) {
        #pragma unroll
        for (int s4 = 0; s4 < 4; ++s4)
          #pragma unroll
          for (int r = 0; r < 4; ++r)
            if (s4*16 + g*4 + r > lq) st[s4][r] = -3.0e38f;
      }

      // online softmax (exp2 domain), defer-max
      float tmax = st[0][0];
      #pragma unroll
      for (int s4 = 0; s4 < 4; ++s4)
        #pragma unroll
        for (int r = 0; r < 4; ++r) tmax = fmaxf(tmax, st[s4][r]);
      tmax = fmaxf(tmax, __shfl_xor(tmax, 16));
      tmax = fmaxf(tmax, __shfl_xor(tmax, 32));
      if (!__all(tmax - mrun <= 11.5f)) {
        float mnew = fmaxf(mrun, tmax);
        float fac = exp2_fast(mrun - mnew);
        #pragma unroll
        for (int r = 0; r < 4; ++r) {
          float fr = __shfl(fac, g*4 + r);
          #pragma unroll
          for (int nf = 0; nf < 4; ++nf) yacc[nf][r] *= fr;
        }
        srun *= fac;
        mrun = mnew;
      }
      float tsum = 0.f;
      #pragma unroll
      for (int s4 = 0; s4 < 4; ++s4)
        #pragma unroll
        for (int r = 0; r < 4; ++r) {
          float pv = exp2_fast(st[s4][r] - mrun);
          st[s4][r] = pv;
          tsum += pv;
        }
      tsum += __shfl_xor(tsum, 16);
      tsum += __shfl_xor(tsum, 32);
      srun += tsum;

      // P -> per-wave LDS (bf16 via cvt_pk; same-wave, no barrier)
      #pragma unroll
      for (int s4 = 0; s4 < 4; ++s4) {
        uint2 pw;
        pw.x = cvt_pk_bf16(st[s4][0], st[s4][1]);
        pw.y = cvt_pk_bf16(st[s4][2], st[s4][3]);
        *(uint2*)&Ps[w][offPw[s4]] = pw;
      }

      // O += P * V
      #pragma unroll
      for (int c = 0; c < 2; ++c) {
        bf16x8 pa = *(const bf16x8*)&Ps[w][offPr[c]];
        #pragma unroll
        for (int nf = 0; nf < 4; ++nf) {
          bf16x8 vf = *(const bf16x8*)&Vs[cur][offK[c][nf]];
          yacc[nf] = __builtin_amdgcn_mfma_f32_16x16x32_bf16(pa, vf, yacc[nf], 0, 0, 0);
        }
      }

      __syncthreads();   // drains prefetch (vmcnt) + guards buf reuse
      cur ^= 1;
    }

    // epilogue for this tile
    #pragma unroll
    for (int r = 0; r < 4; ++r) {
      float sv = __shfl(srun, g*4 + r);
      float inv = 1.f / sv;
      int qg = qrow + g*4 + r;
      #pragma unroll
      for (int nf = 0; nf < 4; ++nf) {
        int d = nf*16 + qi;
        yout[((size_t)bidx*SEQ + qg)*CH + h*HDIM + d] = f2b(yacc[nf][r] * inv);
      }
    }
  }
}

extern "C" void kernel_launch(void* const* d_in, const int* in_sizes, int n_in,
                              void* d_out, int out_size, void* d_ws, size_t ws_size,
                              hipStream_t stream) {
  (void)in_sizes; (void)n_in; (void)out_size; (void)ws_size;
  const void* x      = d_in[0];
  const void* w_attn = d_in[1];
  const void* b_attn = d_in[2];
  const void* w_proj = d_in[3];
  const void* b_proj = d_in[4];

  char* ws = (char*)d_ws;
  const size_t MB = 1024*1024;
  int*   flag = (int*)ws;
  float* ba   = (float*)(ws + 1024);
  float* bp   = (float*)(ws + 16384);
  u16*   xb   = (u16*)(ws + 32768);              // 8 MB, reused as attention out y
  u16*   wat  = (u16*)(ws + 32768 +  8*MB);      // 6 MB  w_attn^T [3072][1024]
  u16*   wpt  = (u16*)(ws + 32768 + 14*MB);      // 2 MB  w_proj^T [1024][1024]
  u16*   qb   = (u16*)(ws + 32768 + 16*MB);      // 8 MB  [bh][t][64]
  u16*   kb   = (u16*)(ws + 32768 + 24*MB);      // 8 MB  [bh][t][64]
  u16*   vtb  = (u16*)(ws + 32768 + 32*MB);      // 8 MB  [bh][64][t]

  csa_detect<<<1, 256, 0, stream>>>((const u16*)x, flag);
  csa_convert_x<<<2048, 256, 0, stream>>>(x, xb, ROWS*CH/8, flag);
  csa_convert_bias<<<12, 256, 0, stream>>>(b_attn, ba, 3*CH, flag);
  csa_convert_bias<<<4, 256, 0, stream>>>(b_proj, bp, CH, flag);
  csa_transpose<<<dim3(96, 32), dim3(32, 8), 0, stream>>>(w_attn, wat, CH, 3*CH, flag);
  csa_transpose<<<dim3(32, 32), dim3(32, 8), 0, stream>>>(w_proj, wpt, CH, CH, flag);

  csa_gemm<<<dim3(24, 32), 256, 0, stream>>>(xb, wat, ba, 3*CH, CH, 0,
                                             qb, kb, vtb, flag);
  csa_attn<<<dim3(32, 16), 256, 0, stream>>>(qb, kb, vtb, xb);
  csa_gemm<<<dim3(8, 32), 256, 0, stream>>>(xb, wpt, bp, CH, CH, 1,
                                            d_out, nullptr, nullptr, flag);
}

// Round 5
// 118.882 us; speedup vs baseline: 1.2834x; 1.2834x over previous
//
#include <hip/hip_runtime.h>

typedef unsigned short u16;
typedef short bf16x8 __attribute__((ext_vector_type(8)));
typedef float f32x4 __attribute__((ext_vector_type(4)));

#define BATCH 2
#define SEQ   2048
#define CH    1024
#define NHEAD 16
#define HDIM  64
#define ROWS  (BATCH*SEQ)   // 4096

// swizzled LDS index for [*][64] bf16 tiles: breaks 128B-row bank conflicts
#define SWZ(r_, c_) (((r_)*64) + ((c_) ^ (((r_)&7)*8)))

__device__ __forceinline__ u16 f2b(float f) {
  unsigned u = __builtin_bit_cast(unsigned, f);
  u += 0x7FFFu + ((u >> 16) & 1u);
  return (u16)(u >> 16);
}
__device__ __forceinline__ float b2f(u16 h) {
  unsigned u = ((unsigned)h) << 16;
  return __builtin_bit_cast(float, u);
}
__device__ __forceinline__ float exp2_fast(float x) {
  float r; asm("v_exp_f32 %0, %1" : "=v"(r) : "v"(x)); return r;
}
__device__ __forceinline__ unsigned cvt_pk_bf16(float a, float b) {
  unsigned r; asm("v_cvt_pk_bf16_f32 %0, %1, %2" : "=v"(r) : "v"(a), "v"(b)); return r;
}

__device__ __forceinline__ void gload_lds16(const void* g, void* l) {
  __builtin_amdgcn_global_load_lds(
      (const __attribute__((address_space(1))) unsigned int*)g,
      (__attribute__((address_space(3))) unsigned int*)l, 16, 0, 0);
}

// ---------- x (f32) -> bf16 [4096][1024] ----------
__global__ void csa_convert_x(const float* __restrict__ in, u16* __restrict__ out,
                              int n8) {
  int i = blockIdx.x * 256 + threadIdx.x;
  if (i >= n8) return;
  const float4* f4 = (const float4*)in;
  float4 v0 = f4[2*i], v1 = f4[2*i+1];
  ushort4 o0, o1;
  o0.x = f2b(v0.x); o0.y = f2b(v0.y); o0.z = f2b(v0.z); o0.w = f2b(v0.w);
  o1.x = f2b(v1.x); o1.y = f2b(v1.y); o1.z = f2b(v1.z); o1.w = f2b(v1.w);
  ((ushort4*)out)[2*i]   = o0;
  ((ushort4*)out)[2*i+1] = o1;
}

// ---------- both weights [1024][C] f32 -> Wt [C][1024] bf16, one launch ----------
__global__ void csa_transpose2(const float* __restrict__ wa, const float* __restrict__ wp,
                               u16* __restrict__ wat, u16* __restrict__ wpt) {
  __shared__ float tile[32][33];
  int bx = blockIdx.x;
  const float* in; u16* out; int C;
  if (bx < 96) { in = wa; out = wat; C = 3*CH; }
  else         { in = wp; out = wpt; C = CH; bx -= 96; }
  const int R = CH;
  const int bxc = bx * 32, by = blockIdx.y * 32;
  const int tx = threadIdx.x, ty = threadIdx.y;
  #pragma unroll
  for (int j = 0; j < 4; ++j) {
    int r = by + ty + j*8, c = bxc + tx;
    tile[ty + j*8][tx] = in[(size_t)r*C + c];
  }
  __syncthreads();
  #pragma unroll
  for (int j = 0; j < 4; ++j) {
    int oc = bxc + ty + j*8;   // column of in = row of out
    int orr = by + tx;         // row of in   = col of out
    out[(size_t)oc*R + orr] = f2b(tile[tx][ty + j*8]);
  }
}

// ---------- QKV GEMM: [4096][3072] = xb[4096][1024] * wat[3072][1024]^T + b ----
// BM=256, BN=192, BK=64; 512 thr = 8 waves (2M x 4N), per-wave 128x48.
// Grid 16x16 = 256 blocks = exactly 1/CU. 2-phase single-barrier dbuf.
// 2D-chunk XCD swizzle: each XCD gets a 4bm x 8bn region (~5MB footprint).
__global__ __launch_bounds__(512) void csa_gemm_qkv(
    const u16* __restrict__ A, const u16* __restrict__ Bt,
    const float* __restrict__ bias,
    u16* __restrict__ qbo, u16* __restrict__ kb, u16* __restrict__ vtb)
{
  __shared__ __align__(16) u16 As[2][256*64];   // 64 KB
  __shared__ __align__(16) u16 Bs[2][192*64];   // 48 KB
  const int t = threadIdx.x, lane = t & 63, w = t >> 6;
  const int wm = w >> 2, wn = w & 3, g = lane >> 4, qi = lane & 15;

  // bijective 2D-chunk swizzle over the 16x16 grid (8 chunks of 4bm x 8bn)
  const int wgid = blockIdx.y * 16 + blockIdx.x;
  const int c8 = wgid & 7, inner = wgid >> 3;
  const int bm = (c8 >> 1) * 4 + (inner >> 3);   // 0..15
  const int bn = (c8 & 1) * 8 + (inner & 7);     // 0..15

  f32x4 acc[8][3] = {};

  const u16* Ab = A  + (size_t)(bm*256)*CH;
  const u16* Bb = Bt + (size_t)(bn*192)*CH;
  const int srow = t >> 3;          // 0..63
  const int scol = (t & 7) * 8;

  // prologue: stage k0=0 into buf 0
  #pragma unroll
  for (int p = 0; p < 4; ++p)
    gload_lds16(Ab + (size_t)(p*64 + srow)*CH + scol, &As[0][p*4096 + w*512]);
  #pragma unroll
  for (int p = 0; p < 3; ++p)
    gload_lds16(Bb + (size_t)(p*64 + srow)*CH + scol, &Bs[0][p*4096 + w*512]);
  __syncthreads();

  int cur = 0;
  for (int k0 = 0; k0 < CH; k0 += 64) {
    if (k0 + 64 < CH) {   // prefetch next K-tile into buf^1
      #pragma unroll
      for (int p = 0; p < 4; ++p)
        gload_lds16(Ab + (size_t)(p*64 + srow)*CH + (k0+64) + scol, &As[cur^1][p*4096 + w*512]);
      #pragma unroll
      for (int p = 0; p < 3; ++p)
        gload_lds16(Bb + (size_t)(p*64 + srow)*CH + (k0+64) + scol, &Bs[cur^1][p*4096 + w*512]);
    }
    #pragma unroll
    for (int kk = 0; kk < 2; ++kk) {
      bf16x8 af[8], bfr[3];
      #pragma unroll
      for (int m = 0; m < 8; ++m)
        af[m] = *(const bf16x8*)&As[cur][(wm*128 + m*16 + qi)*64 + kk*32 + g*8];
      #pragma unroll
      for (int n = 0; n < 3; ++n)
        bfr[n] = *(const bf16x8*)&Bs[cur][(wn*48 + n*16 + qi)*64 + kk*32 + g*8];
      #pragma unroll
      for (int m = 0; m < 8; ++m)
        #pragma unroll
        for (int n = 0; n < 3; ++n)
          acc[m][n] = __builtin_amdgcn_mfma_f32_16x16x32_bf16(af[m], bfr[n], acc[m][n], 0, 0, 0);
    }
    __syncthreads();   // drains prefetch + guards buffer reuse
    cur ^= 1;
  }

  // epilogue: scatter to q/k [bh][t][64] and v^T [bh][64][t]
  #pragma unroll
  for (int m = 0; m < 8; ++m) {
    const int row0 = bm*256 + wm*128 + m*16 + g*4;
    const int bb = row0 >> 11;          // batch (4-row group never crosses)
    const int t0 = row0 & 2047;
    #pragma unroll
    for (int n = 0; n < 3; ++n) {
      const int col = bn*192 + wn*48 + n*16 + qi;   // fragment never straddles 1024
      const float bv = bias[col];
      const int which = col >> 10;      // 0=q 1=k 2=v
      const int cc = col & 1023;
      const int h = cc >> 6, d = cc & 63;
      const int bh = bb*16 + h;
      if (which == 2) {
        ushort4 pw;
        pw.x = f2b(acc[m][n][0] + bv);
        pw.y = f2b(acc[m][n][1] + bv);
        pw.z = f2b(acc[m][n][2] + bv);
        pw.w = f2b(acc[m][n][3] + bv);
        *(ushort4*)&vtb[((size_t)bh*HDIM + d)*SEQ + t0] = pw;
      } else {
        u16* dst = (which == 0) ? qbo : kb;
        #pragma unroll
        for (int r = 0; r < 4; ++r)
          dst[((size_t)bh*SEQ + t0 + r)*HDIM + d] = f2b(acc[m][n][r] + bv);
      }
    }
  }
}

// ---------- proj GEMM: out[4096][1024] f32 = y[4096][1024] * wpt^T + b ----------
// 128x128 tile, 2-phase dbuf, plain block mapping (grid 8x32 = 256 = 1/CU).
__global__ __launch_bounds__(256) void csa_gemm_proj(
    const u16* __restrict__ A, const u16* __restrict__ Bt,
    const float* __restrict__ bias, float* __restrict__ out)
{
  __shared__ __align__(16) u16 As[2][128*64];
  __shared__ __align__(16) u16 Bs[2][128*64];
  const int t = threadIdx.x, lane = t & 63, w = t >> 6;
  const int wm = w >> 1, wn = w & 1, g = lane >> 4, qi = lane & 15;
  const int bm = blockIdx.y, bn = blockIdx.x;

  f32x4 acc[4][4] = {};

  const u16* Ab = A  + (size_t)(bm*128)*CH;
  const u16* Bb = Bt + (size_t)(bn*128)*CH;
  const int srow = t >> 3;
  const int scol = (t & 7) * 8;

  #pragma unroll
  for (int p = 0; p < 4; ++p) {
    gload_lds16(Ab + (size_t)(p*32 + srow)*CH + scol, &As[0][p*2048 + w*512]);
    gload_lds16(Bb + (size_t)(p*32 + srow)*CH + scol, &Bs[0][p*2048 + w*512]);
  }
  __syncthreads();

  int cur = 0;
  for (int k0 = 0; k0 < CH; k0 += 64) {
    if (k0 + 64 < CH) {
      #pragma unroll
      for (int p = 0; p < 4; ++p) {
        gload_lds16(Ab + (size_t)(p*32 + srow)*CH + (k0+64) + scol, &As[cur^1][p*2048 + w*512]);
        gload_lds16(Bb + (size_t)(p*32 + srow)*CH + (k0+64) + scol, &Bs[cur^1][p*2048 + w*512]);
      }
    }
    #pragma unroll
    for (int kk = 0; kk < 2; ++kk) {
      bf16x8 af[4], bfr[4];
      #pragma unroll
      for (int m = 0; m < 4; ++m)
        af[m] = *(const bf16x8*)&As[cur][(wm*64 + m*16 + qi)*64 + kk*32 + g*8];
      #pragma unroll
      for (int n = 0; n < 4; ++n)
        bfr[n] = *(const bf16x8*)&Bs[cur][(wn*64 + n*16 + qi)*64 + kk*32 + g*8];
      #pragma unroll
      for (int m = 0; m < 4; ++m)
        #pragma unroll
        for (int n = 0; n < 4; ++n)
          acc[m][n] = __builtin_amdgcn_mfma_f32_16x16x32_bf16(af[m], bfr[n], acc[m][n], 0, 0, 0);
    }
    __syncthreads();
    cur ^= 1;
  }

  #pragma unroll
  for (int m = 0; m < 4; ++m) {
    const int row0 = bm*128 + wm*64 + m*16 + g*4;
    #pragma unroll
    for (int n = 0; n < 4; ++n) {
      const int col = bn*128 + wn*64 + n*16 + qi;
      const float bv = bias[col];
      #pragma unroll
      for (int r = 0; r < 4; ++r)
        out[(size_t)(row0 + r)*CH + col] = acc[m][n][r] + bv;
    }
  }
}

// ---------- causal flash attention (unchanged from round 3/4) ----------
__global__ __launch_bounds__(256) void csa_attn(
    const u16* __restrict__ qb, const u16* __restrict__ kb,
    const u16* __restrict__ vtb, u16* __restrict__ yout)
{
  const int bh = blockIdx.x, pair = blockIdx.y;
  const int bidx = bh >> 4, h = bh & 15;
  const int t = threadIdx.x, lane = t & 63, w = t >> 6;
  const int g = lane >> 4, qi = lane & 15;
  __shared__ __align__(16) u16 Ks[2][64*64];
  __shared__ __align__(16) u16 Vs[2][64*64];    // V^T tile: [d][key]
  __shared__ __align__(16) u16 Ps[4][16*64];    // per-wave P [q][key] (no barrier)

  const size_t kvbase = (size_t)bh * SEQ * HDIM;   // == bh*HDIM*SEQ for vtb
  const int srow = t >> 3;
  const int ssw  = ((t >> 3) & 7) * 8;
  const int scol = ((t & 7) * 8) ^ ssw;  // pre-swizzled source column

  int offK[2][4], offPw[4], offPr[2];
  #pragma unroll
  for (int c = 0; c < 2; ++c) {
    offPr[c] = SWZ(qi, c*32 + g*8);
    #pragma unroll
    for (int s4 = 0; s4 < 4; ++s4) offK[c][s4] = SWZ(s4*16 + qi, c*32 + g*8);
  }
  #pragma unroll
  for (int s4 = 0; s4 < 4; ++s4) offPw[s4] = SWZ(qi, s4*16 + g*4);

  const float QSCALE = 0.18033688011112042f;   // 0.125 * log2(e)
  const int lq = w*16 + qi;

  for (int half = 0; half < 2; ++half) {
    const int qt = half ? (31 - pair) : pair;
    const int qrow = qt*64 + w*16;
    const int nkt = qt + 1;

    bf16x8 qf[2];
    #pragma unroll
    for (int c = 0; c < 2; ++c) {
      qf[c] = *(const bf16x8*)&qb[(kvbase + (size_t)(qrow + qi)*HDIM) + c*32 + g*8];
      #pragma unroll
      for (int e = 0; e < 8; ++e)
        qf[c][e] = (short)f2b(b2f((u16)qf[c][e]) * QSCALE);
    }

    f32x4 yacc[4] = {};
    float mrun = -1e30f, srun = 0.f;

    #pragma unroll
    for (int p = 0; p < 2; ++p) {
      int row = p*32 + srow;
      gload_lds16(kb  + kvbase + (size_t)row*HDIM + scol, &Ks[0][p*2048 + w*512]);
      gload_lds16(vtb + kvbase + (size_t)row*SEQ  + scol, &Vs[0][p*2048 + w*512]);
    }
    __syncthreads();

    int cur = 0;
    for (int kt = 0; kt < nkt; ++kt) {
      if (kt + 1 < nkt) {
        const int k1 = (kt + 1) * 64;
        #pragma unroll
        for (int p = 0; p < 2; ++p) {
          int row = p*32 + srow;
          gload_lds16(kb  + kvbase + (size_t)(k1 + row)*HDIM + scol, &Ks[cur^1][p*2048 + w*512]);
          gload_lds16(vtb + kvbase + (size_t)row*SEQ + k1 + scol,    &Vs[cur^1][p*2048 + w*512]);
        }
      }

      f32x4 st[4] = {};
      #pragma unroll
      for (int c = 0; c < 2; ++c)
        #pragma unroll
        for (int s4 = 0; s4 < 4; ++s4) {
          bf16x8 kf = *(const bf16x8*)&Ks[cur][offK[c][s4]];
          st[s4] = __builtin_amdgcn_mfma_f32_16x16x32_bf16(kf, qf[c], st[s4], 0, 0, 0);
        }

      if (kt == nkt - 1) {
        #pragma unroll
        for (int s4 = 0; s4 < 4; ++s4)
          #pragma unroll
          for (int r = 0; r < 4; ++r)
            if (s4*16 + g*4 + r > lq) st[s4][r] = -3.0e38f;
      }

      float tmax = st[0][0];
      #pragma unroll
      for (int s4 = 0; s4 < 4; ++s4)
        #pragma unroll
        for (int r = 0; r < 4; ++r) tmax = fmaxf(tmax, st[s4][r]);
      tmax = fmaxf(tmax, __shfl_xor(tmax, 16));
      tmax = fmaxf(tmax, __shfl_xor(tmax, 32));
      if (!__all(tmax - mrun <= 11.5f)) {
        float mnew = fmaxf(mrun, tmax);
        float fac = exp2_fast(mrun - mnew);
        #pragma unroll
        for (int r = 0; r < 4; ++r) {
          float fr = __shfl(fac, g*4 + r);
          #pragma unroll
          for (int nf = 0; nf < 4; ++nf) yacc[nf][r] *= fr;
        }
        srun *= fac;
        mrun = mnew;
      }
      float tsum = 0.f;
      #pragma unroll
      for (int s4 = 0; s4 < 4; ++s4)
        #pragma unroll
        for (int r = 0; r < 4; ++r) {
          float pv = exp2_fast(st[s4][r] - mrun);
          st[s4][r] = pv;
          tsum += pv;
        }
      tsum += __shfl_xor(tsum, 16);
      tsum += __shfl_xor(tsum, 32);
      srun += tsum;

      #pragma unroll
      for (int s4 = 0; s4 < 4; ++s4) {
        uint2 pw;
        pw.x = cvt_pk_bf16(st[s4][0], st[s4][1]);
        pw.y = cvt_pk_bf16(st[s4][2], st[s4][3]);
        *(uint2*)&Ps[w][offPw[s4]] = pw;
      }

      #pragma unroll
      for (int c = 0; c < 2; ++c) {
        bf16x8 pa = *(const bf16x8*)&Ps[w][offPr[c]];
        #pragma unroll
        for (int nf = 0; nf < 4; ++nf) {
          bf16x8 vf = *(const bf16x8*)&Vs[cur][offK[c][nf]];
          yacc[nf] = __builtin_amdgcn_mfma_f32_16x16x32_bf16(pa, vf, yacc[nf], 0, 0, 0);
        }
      }

      __syncthreads();
      cur ^= 1;
    }

    #pragma unroll
    for (int r = 0; r < 4; ++r) {
      float sv = __shfl(srun, g*4 + r);
      float inv = 1.f / sv;
      int qg = qrow + g*4 + r;
      #pragma unroll
      for (int nf = 0; nf < 4; ++nf) {
        int d = nf*16 + qi;
        yout[((size_t)bidx*SEQ + qg)*CH + h*HDIM + d] = f2b(yacc[nf][r] * inv);
      }
    }
  }
}

extern "C" void kernel_launch(void* const* d_in, const int* in_sizes, int n_in,
                              void* d_out, int out_size, void* d_ws, size_t ws_size,
                              hipStream_t stream) {
  (void)in_sizes; (void)n_in; (void)out_size; (void)ws_size;
  const float* x      = (const float*)d_in[0];
  const float* w_attn = (const float*)d_in[1];
  const float* b_attn = (const float*)d_in[2];
  const float* w_proj = (const float*)d_in[3];
  const float* b_proj = (const float*)d_in[4];

  char* ws = (char*)d_ws;
  const size_t MB = 1024*1024;
  u16* xb  = (u16*)(ws);             // 8 MB, reused as attention out y
  u16* wat = (u16*)(ws +  8*MB);     // 6 MB  w_attn^T [3072][1024]
  u16* wpt = (u16*)(ws + 14*MB);     // 2 MB  w_proj^T [1024][1024]
  u16* qb  = (u16*)(ws + 16*MB);     // 8 MB  [bh][t][64]
  u16* kb  = (u16*)(ws + 24*MB);     // 8 MB  [bh][t][64]
  u16* vtb = (u16*)(ws + 32*MB);     // 8 MB  [bh][64][t]

  csa_convert_x<<<2048, 256, 0, stream>>>(x, xb, ROWS*CH/8);
  csa_transpose2<<<dim3(128, 32), dim3(32, 8), 0, stream>>>(w_attn, w_proj, wat, wpt);
  csa_gemm_qkv<<<dim3(16, 16), 512, 0, stream>>>(xb, wat, b_attn, qb, kb, vtb);
  csa_attn<<<dim3(32, 16), 256, 0, stream>>>(qb, kb, vtb, xb);
  csa_gemm_proj<<<dim3(8, 32), 256, 0, stream>>>(xb, wpt, b_proj, (float*)d_out);
}